// Round 4
// baseline (886.794 us; speedup 1.0000x reference)
//
#include <hip/hip_runtime.h>

#define NPOS (16*128*128)   // B*H*W = 262144
#define HWN  16384          // H*W

typedef float v2f __attribute__((ext_vector_type(2)));

// workspace float offsets
#define WS_WMUT  0          // [152][128] transposed Wmu (row = input channel, col = output)
#define WS_WSIGT 19456      // [152][8]   transposed Wsig
#define WS_WPI   20672      // [8][16]
#define WS_BPI   20800      // [8]
#define WS_BMU   20808      // [128]
#define WS_BSIG  20936      // [8]
#define WS_WG    20944      // [8]
#define WS_BG    20952      // [1]
#define WS_TOTAL 20953

__global__ __launch_bounds__(256) void prep_weights(
    const float* __restrict__ Wpi, const float* __restrict__ bpi,
    const float* __restrict__ Wmu, const float* __restrict__ bmu,
    const float* __restrict__ Wsig, const float* __restrict__ bsig,
    const float* __restrict__ Wg,  const float* __restrict__ bg,
    float* __restrict__ ws)
{
  int i = blockIdx.x*256 + threadIdx.x;
  if (i < 19456){ int c = i >> 7, o = i & 127; ws[WS_WMUT + i] = Wmu[o*152 + c]; return; }
  i -= 19456;
  if (i < 1216){ int c = i >> 3, j = i & 7; ws[WS_WSIGT + i] = Wsig[j*152 + c]; return; }
  i -= 1216;
  if (i < 128){ ws[WS_WPI + i] = Wpi[i]; return; }
  i -= 128;
  if (i < 8){ ws[WS_BPI + i] = bpi[i]; return; }
  i -= 8;
  if (i < 128){ ws[WS_BMU + i] = bmu[i]; return; }
  i -= 128;
  if (i < 8){ ws[WS_BSIG + i] = bsig[i]; return; }
  i -= 8;
  if (i < 8){ ws[WS_WG + i] = Wg[i]; return; }
  i -= 8;
  if (i < 1){ ws[WS_BG] = bg[0]; }
}

__device__ __forceinline__ v2f pkfma(v2f a, v2f b, v2f c){
#if __has_builtin(__builtin_elementwise_fma)
  return __builtin_elementwise_fma(a, b, c);
#else
  v2f r; r.x = __builtin_fmaf(a.x, b.x, c.x); r.y = __builtin_fmaf(a.y, b.y, c.y); return r;
#endif
}

// consume one 32-channel LDS tile into 32 packed accumulators (64 outputs)
template<int KOFF, bool D1>
__device__ __forceinline__ void consume_tile(const float* __restrict__ WmuT,
    const float* smu, float* smd, const float* xv, v2f* a2, int tile, int tid)
{
  #pragma unroll
  for (int h = 0; h < 2; ++h){
    float dk = 0.f;
    #pragma unroll
    for (int cc = 0; cc < 16; ++cc){
      float v = smu[(h*16 + cc)*256 + tid];
      if (D1){ float t = xv[cc] - v; dk = __builtin_fmaf(t, t, dk); }
      v2f vv; vv.x = v; vv.y = v;
      const v2f* w2 = (const v2f*)(WmuT + (16 + tile*32 + h*16 + cc)*128 + KOFF);
      #pragma unroll
      for (int j = 0; j < 32; ++j) a2[j] = pkfma(w2[j], vv, a2[j]);
    }
    if (D1) smd[(2*tile + h)*256 + tid] = dk;   // dist1 partial for component 2*tile+h
  }
}

template<int KOFF>
__device__ __forceinline__ void add_xrho(const float* __restrict__ WmuT,
    const float* xv, const float* rhov, v2f* a2)
{
  #pragma unroll
  for (int r = 0; r < 16; ++r){
    v2f vv; vv.x = xv[r]; vv.y = xv[r];
    const v2f* w2 = (const v2f*)(WmuT + r*128 + KOFF);
    #pragma unroll
    for (int j = 0; j < 32; ++j) a2[j] = pkfma(w2[j], vv, a2[j]);
  }
  #pragma unroll
  for (int r = 0; r < 8; ++r){
    v2f vv; vv.x = rhov[r]; vv.y = rhov[r];
    const v2f* w2 = (const v2f*)(WmuT + (144 + r)*128 + KOFF);
    #pragma unroll
    for (int j = 0; j < 32; ++j) a2[j] = pkfma(w2[j], vv, a2[j]);
  }
}

// relu + store + dist2 + sigma accumulation for 64 outputs (chunk KC)
template<int KC>
__device__ __forceinline__ void epilogue(const float* __restrict__ WsigT,
    const float* xv, const v2f* a2, v2f* sacc2, float* d2v, float* out_mu)
{
  #pragma unroll
  for (int j = 0; j < 64; ++j){
    float raw = (j & 1) ? a2[j>>1].y : a2[j>>1].x;
    float mn = fmaxf(raw, 0.f);
    out_mu[(KC*64 + j)*HWN] = mn;
    float t = xv[j & 15] - mn;
    d2v[KC*4 + (j>>4)] = __builtin_fmaf(t, t, d2v[KC*4 + (j>>4)]);
    v2f mm; mm.x = mn; mm.y = mn;
    const v2f* wsg = (const v2f*)(WsigT + (16 + KC*64 + j)*8);
    #pragma unroll
    for (int q = 0; q < 4; ++q) sacc2[q] = pkfma(wsg[q], mm, sacc2[q]);
  }
}

__global__ __launch_bounds__(256, 4) void gmm_fused(
    const float* __restrict__ x,
    const float* __restrict__ pi,
    const float* __restrict__ mu,
    const float* __restrict__ sigma,
    const float* __restrict__ ws,
    float* __restrict__ out)
{
  __shared__ float smu[8192];   // 32 channels x 256 positions (32 KB)
  __shared__ float smd[2048];   // dist1[8] per position (8 KB)

  const int tid  = threadIdx.x;
  const int lane = tid & 63;
  const int wv   = tid >> 6;
  const int bidx = blockIdx.x;
  const int b    = bidx >> 6;           // 64 blocks per batch image
  const int pos0 = (bidx & 63) << 8;    // strip start within hw
  const int hw   = pos0 + tid;
  const int p    = bidx*256 + tid;

  const float* mublk = mu + b*2097152 + pos0;
  const float* xb    = x  + b*262144 + hw;
  const float* WmuT  = ws + WS_WMUT;
  const float* WsigT = ws + WS_WSIGT;
  const float* bmu   = ws + WS_BMU;

  float xv[16];
  #pragma unroll
  for (int c = 0; c < 16; ++c) xv[c] = xb[c*HWN];

  v2f a2[32];
  #pragma unroll
  for (int j = 0; j < 32; ++j){ a2[j].x = bmu[2*j]; a2[j].y = bmu[2*j+1]; }

  // ---- chunk 0 (outputs 0..63) over 4 LDS tiles, dist1 fused ----
  #pragma unroll 1
  for (int tile = 0; tile < 4; ++tile){
    #pragma unroll
    for (int i = 0; i < 8; ++i){
      int row = wv*8 + i;
      float4 t4 = *(const float4*)(mublk + (tile*32 + row)*HWN + lane*4);
      *(float4*)(&smu[row*256 + lane*4]) = t4;
    }
    __syncthreads();
    consume_tile<0, true>(WmuT, smu, smd, xv, a2, tile, tid);
    __syncthreads();
  }

  // ---- rho (needs pi, sigma, full dist1) ----
  float rhov[8];
  #pragma unroll
  for (int k = 0; k < 8; ++k){
    float pv = pi[b*131072 + k*HWN + hw];
    float s  = sigma[b*131072 + k*HWN + hw];
    float s2 = s*s;
    float d1 = smd[k*256 + tid];
    float p1 = 6.2831853071795864f * s2;
    float p2 = p1*p1, p4 = p2*p2, p8 = p4*p4;
    float dens = __expf(-0.5f * d1 / s2) / p8;
    rhov[k] = pv * dens * dens;
  }

  add_xrho<0>(WmuT, xv, rhov, a2);

  // ---- sigma accumulators: bias + x-part + rho-part (packed) ----
  v2f sacc2[4];
  {
    const float* bs = ws + WS_BSIG;
    #pragma unroll
    for (int q = 0; q < 4; ++q){ sacc2[q].x = bs[2*q]; sacc2[q].y = bs[2*q+1]; }
    #pragma unroll
    for (int c = 0; c < 16; ++c){
      v2f vv; vv.x = xv[c]; vv.y = xv[c];
      const v2f* wsg = (const v2f*)(WsigT + c*8);
      #pragma unroll
      for (int q = 0; q < 4; ++q) sacc2[q] = pkfma(wsg[q], vv, sacc2[q]);
    }
    #pragma unroll
    for (int r = 0; r < 8; ++r){
      v2f vv; vv.x = rhov[r]; vv.y = rhov[r];
      const v2f* wsg = (const v2f*)(WsigT + (144 + r)*8);
      #pragma unroll
      for (int q = 0; q < 4; ++q) sacc2[q] = pkfma(wsg[q], vv, sacc2[q]);
    }
  }

  float d2v[8];
  #pragma unroll
  for (int k = 0; k < 8; ++k) d2v[k] = 0.f;

  float* out_mu = out + 2097152 + b*2097152 + hw;
  epilogue<0>(WsigT, xv, a2, sacc2, d2v, out_mu);

  // ---- chunk 1 (outputs 64..127) ----
  #pragma unroll
  for (int j = 0; j < 32; ++j){ a2[j].x = bmu[64 + 2*j]; a2[j].y = bmu[64 + 2*j+1]; }

  #pragma unroll 1
  for (int tile = 0; tile < 4; ++tile){
    #pragma unroll
    for (int i = 0; i < 8; ++i){
      int row = wv*8 + i;
      float4 t4 = *(const float4*)(mublk + (tile*32 + row)*HWN + lane*4);
      *(float4*)(&smu[row*256 + lane*4]) = t4;
    }
    __syncthreads();
    consume_tile<64, false>(WmuT, smu, smd, xv, a2, tile, tid);
    __syncthreads();
  }

  add_xrho<64>(WmuT, xv, rhov, a2);
  epilogue<1>(WsigT, xv, a2, sacc2, d2v, out_mu);

  // ---- sigma_new + dens2 ----
  float dens2v[8];
  float* out_sig = out + 35651584 + b*131072 + hw;
  #pragma unroll
  for (int k = 0; k < 8; ++k){
    float sl = (k & 1) ? sacc2[k>>1].y : sacc2[k>>1].x;
    float sn = __expf(fmaxf(sl, 0.f));
    out_sig[k*HWN] = sn;
    float s2 = sn*sn;
    float p1 = 6.2831853071795864f * s2;
    float p2 = p1*p1, p4 = p2*p2, p8 = p4*p4;
    dens2v[k] = __expf(-0.5f * d2v[k] / s2) / p8;
  }

  // ---- pi_new (dens1 recomputed from smd) + gamma ----
  {
    float piv[8], alphav[8];
    #pragma unroll
    for (int k = 0; k < 8; ++k){
      float pv = pi[b*131072 + k*HWN + hw];
      float s  = sigma[b*131072 + k*HWN + hw];
      float s2 = s*s;
      float d1 = smd[k*256 + tid];
      float p1 = 6.2831853071795864f * s2;
      float p2 = p1*p1, p4 = p2*p2, p8 = p4*p4;
      float dens = __expf(-0.5f * d1 / s2) / p8;
      piv[k] = pv;
      alphav[k] = pv * dens;
    }
    const float* Wpi = ws + WS_WPI;
    const float* bpi = ws + WS_BPI;
    float logit[8], mx = -1e30f;
    #pragma unroll
    for (int j = 0; j < 8; ++j){
      float a = bpi[j];
      #pragma unroll
      for (int k = 0; k < 8; ++k) a = __builtin_fmaf(Wpi[j*16 + k],     piv[k],    a);
      #pragma unroll
      for (int k = 0; k < 8; ++k) a = __builtin_fmaf(Wpi[j*16 + 8 + k], alphav[k], a);
      logit[j] = a;
      mx = fmaxf(mx, a);
    }
    float pin[8], ssum = 0.f;
    #pragma unroll
    for (int j = 0; j < 8; ++j){ pin[j] = __expf(logit[j] - mx); ssum += pin[j]; }
    float rs = 1.f / ssum;
    float* out_pi = out + b*131072 + hw;
    const float* Wg = ws + WS_WG;
    float g = ws[WS_BG];
    #pragma unroll
    for (int j = 0; j < 8; ++j){
      float pn = pin[j] * rs;
      out_pi[j*HWN] = pn;
      g = __builtin_fmaf(Wg[j], pn * dens2v[j], g);
    }
    out[37748736 + p] = 1.f / (1.f + __expf(-g));
  }
}

extern "C" void kernel_launch(void* const* d_in, const int* in_sizes, int n_in,
                              void* d_out, int out_size, void* d_ws, size_t ws_size,
                              hipStream_t stream)
{
  const float* x    = (const float*)d_in[0];
  const float* pi   = (const float*)d_in[1];
  const float* mu   = (const float*)d_in[2];
  const float* sg   = (const float*)d_in[3];
  const float* Wpi  = (const float*)d_in[4];
  const float* bpi  = (const float*)d_in[5];
  const float* Wmu  = (const float*)d_in[6];
  const float* bmu  = (const float*)d_in[7];
  const float* Wsig = (const float*)d_in[8];
  const float* bsig = (const float*)d_in[9];
  const float* Wg   = (const float*)d_in[10];
  const float* bg   = (const float*)d_in[11];
  float* ws  = (float*)d_ws;
  float* out = (float*)d_out;

  prep_weights<<<(WS_TOTAL + 255)/256, 256, 0, stream>>>(
      Wpi, bpi, Wmu, bmu, Wsig, bsig, Wg, bg, ws);
  gmm_fused<<<NPOS/256, 256, 0, stream>>>(x, pi, mu, sg, ws, out);
}